// Round 1
// baseline (270.328 us; speedup 1.0000x reference)
//
#include <hip/hip_runtime.h>

// ---------- types ----------
typedef __bf16 bf16x8 __attribute__((ext_vector_type(8)));
typedef float f32x4 __attribute__((ext_vector_type(4)));
typedef unsigned short u16x8 __attribute__((ext_vector_type(8)));

__device__ __forceinline__ unsigned short f2bf(float f) {
  union { float f; unsigned int u; } v; v.f = f;
  unsigned int r = v.u + 0x7FFFu + ((v.u >> 16) & 1u);
  return (unsigned short)(r >> 16);
}
__device__ __forceinline__ float bf2f(unsigned short h) {
  union { unsigned int u; float f; } v; v.u = ((unsigned int)h) << 16;
  return v.f;
}

// global -> LDS direct copy, 16B per lane; lds dst is wave-uniform base (+lane*16 by HW)
__device__ __forceinline__ void gload_lds16(const void* g, void* l) {
  __builtin_amdgcn_global_load_lds(
      (const __attribute__((address_space(1))) void*)g,
      (__attribute__((address_space(3))) void*)l, 16, 0, 0);
}

// ---------- conv: depthwise k=3 pad=1, three paths, bf16 out ----------
__global__ __launch_bounds__(256)
void conv3_kernel(const float* __restrict__ x,
                  const float* __restrict__ wq, const float* __restrict__ bq,
                  const float* __restrict__ wk, const float* __restrict__ bk,
                  const float* __restrict__ wv, const float* __restrict__ bv,
                  unsigned short* __restrict__ cq, unsigned short* __restrict__ ck,
                  unsigned short* __restrict__ cv)
{
  int idx = blockIdx.x * 256 + threadIdx.x;   // over B*S*D = 4194304
  int d = idx & 1023;
  int t = idx >> 10;          // b*2048+s
  int s = t & 2047;
  float xc = x[idx];
  float xm = (s > 0)    ? x[idx - 1024] : 0.0f;
  float xp = (s < 2047) ? x[idx + 1024] : 0.0f;
  cq[idx] = f2bf(xm * wq[d*3+0] + xc * wq[d*3+1] + xp * wq[d*3+2] + bq[d]);
  ck[idx] = f2bf(xm * wk[d*3+0] + xc * wk[d*3+1] + xp * wk[d*3+2] + bk[d]);
  cv[idx] = f2bf(xm * wv[d*3+0] + xc * wv[d*3+1] + xp * wv[d*3+2] + bv[d]);
}

// ---------- weight fp32 -> bf16 ----------
__global__ __launch_bounds__(256)
void cvt_w_kernel(const float* __restrict__ w0, const float* __restrict__ w1,
                  const float* __restrict__ w2, const float* __restrict__ w3,
                  unsigned short* __restrict__ o0, unsigned short* __restrict__ o1,
                  unsigned short* __restrict__ o2, unsigned short* __restrict__ o3)
{
  const float* src; unsigned short* dst;
  switch (blockIdx.y) {
    case 0: src = w0; dst = o0; break;
    case 1: src = w1; dst = o1; break;
    case 2: src = w2; dst = o2; break;
    default: src = w3; dst = o3; break;
  }
  int i = blockIdx.x * 1024 + threadIdx.x * 4;   // 1M elements per matrix
  float4 v = *(const float4*)(src + i);
  dst[i+0] = f2bf(v.x); dst[i+1] = f2bf(v.y);
  dst[i+2] = f2bf(v.z); dst[i+3] = f2bf(v.w);
}

// ---------- GEMM core: C[128x128] += A[bm..][K] * W[bn..][K]^T, K=1024, BK=32 ----------
__device__ __forceinline__ void gemm_tile_core(
    const unsigned short* __restrict__ A, const unsigned short* __restrict__ W,
    int bm, int bn, unsigned short* lA, unsigned short* lB, f32x4 acc[4][4])
{
  const int K = 1024;
  const int tid  = threadIdx.x;
  const int lane = tid & 63;
  const int w    = tid >> 6;            // wave 0..3
  const int lrow = lane & 15;
  const int lko  = (lane >> 4) * 8;     // k-offset within 32
  const int wm   = (w >> 1) * 64;
  const int wn   = (w & 1) * 64;

  #pragma unroll
  for (int i = 0; i < 4; i++)
    #pragma unroll
    for (int j = 0; j < 4; j++)
      acc[i][j] = f32x4{0.f, 0.f, 0.f, 0.f};

  for (int k0 = 0; k0 < K; k0 += 32) {
    // stage A and B tiles: 128x32 bf16 = 8KB each = 512 x 16B chunks; 4 chunks/row
    #pragma unroll
    for (int i = 0; i < 2; i++) {
      int ci  = (i * 4 + w) * 64 + lane;
      int row = ci >> 2;
      int kc  = (ci & 3) * 8;
      gload_lds16(A + (size_t)(bm + row) * K + (k0 + kc), lA + (size_t)(i*4 + w) * 512);
      gload_lds16(W + (size_t)(bn + row) * K + (k0 + kc), lB + (size_t)(i*4 + w) * 512);
    }
    __syncthreads();   // compiler drains vmcnt before barrier

    bf16x8 af[4], bfr[4];
    #pragma unroll
    for (int mt = 0; mt < 4; mt++)
      af[mt] = *(const bf16x8*)(lA + (wm + mt*16 + lrow) * 32 + lko);
    #pragma unroll
    for (int nt = 0; nt < 4; nt++)
      bfr[nt] = *(const bf16x8*)(lB + (wn + nt*16 + lrow) * 32 + lko);
    #pragma unroll
    for (int mt = 0; mt < 4; mt++)
      #pragma unroll
      for (int nt = 0; nt < 4; nt++)
        acc[mt][nt] = __builtin_amdgcn_mfma_f32_16x16x32_bf16(af[mt], bfr[nt], acc[mt][nt], 0, 0, 0);
    __syncthreads();
  }
}

// ---------- q/k/v projections, epilogue permutes to [B,H,S,64] bf16 ----------
__global__ __launch_bounds__(256)
void gemm_qkv_kernel(const unsigned short* __restrict__ cq, const unsigned short* __restrict__ ck,
                     const unsigned short* __restrict__ cv,
                     const unsigned short* __restrict__ wqb, const unsigned short* __restrict__ wkb,
                     const unsigned short* __restrict__ wvb,
                     const float* __restrict__ bq, const float* __restrict__ bk,
                     const float* __restrict__ bv,
                     unsigned short* __restrict__ qo, unsigned short* __restrict__ ko,
                     unsigned short* __restrict__ vo)
{
  __shared__ alignas(16) unsigned short lA[128 * 32];
  __shared__ alignas(16) unsigned short lB[128 * 32];
  int z = blockIdx.z;
  const unsigned short* A = (z == 0) ? cq : ((z == 1) ? ck : cv);
  const unsigned short* W = (z == 0) ? wqb : ((z == 1) ? wkb : wvb);
  const float* bias       = (z == 0) ? bq : ((z == 1) ? bk : bv);
  unsigned short* O       = (z == 0) ? qo : ((z == 1) ? ko : vo);
  float scale             = (z == 0) ? 0.125f : 1.0f;   // fold 1/sqrt(64) into Q (exact)

  int bm = blockIdx.y * 128, bn = blockIdx.x * 128;
  f32x4 acc[4][4];
  gemm_tile_core(A, W, bm, bn, lA, lB, acc);

  const int tid = threadIdx.x, lane = tid & 63, w = tid >> 6;
  const int lrow = lane & 15, lgrp = lane >> 4;
  const int wm = (w >> 1) * 64, wn = (w & 1) * 64;
  #pragma unroll
  for (int mt = 0; mt < 4; mt++) {
    #pragma unroll
    for (int nt = 0; nt < 4; nt++) {
      int gn = bn + wn + nt*16 + lrow;
      float bb = bias[gn];
      int h = gn >> 6, dk = gn & 63;
      #pragma unroll
      for (int i = 0; i < 4; i++) {
        int gm = bm + wm + mt*16 + lgrp*4 + i;     // b*2048+s
        int b = gm >> 11, s = gm & 2047;
        float val = (acc[mt][nt][i] + bb) * scale;
        O[((size_t)(b*16 + h) * 2048 + s) * 64 + dk] = f2bf(val);
      }
    }
  }
}

// ---------- final projection: f32 out ----------
__global__ __launch_bounds__(256)
void gemm_out_kernel(const unsigned short* __restrict__ A, const unsigned short* __restrict__ W,
                     const float* __restrict__ bias, float* __restrict__ Out)
{
  __shared__ alignas(16) unsigned short lA[128 * 32];
  __shared__ alignas(16) unsigned short lB[128 * 32];
  int bm = blockIdx.y * 128, bn = blockIdx.x * 128;
  f32x4 acc[4][4];
  gemm_tile_core(A, W, bm, bn, lA, lB, acc);

  const int tid = threadIdx.x, lane = tid & 63, w = tid >> 6;
  const int lrow = lane & 15, lgrp = lane >> 4;
  const int wm = (w >> 1) * 64, wn = (w & 1) * 64;
  #pragma unroll
  for (int mt = 0; mt < 4; mt++) {
    #pragma unroll
    for (int nt = 0; nt < 4; nt++) {
      int gn = bn + wn + nt*16 + lrow;
      float bb = bias[gn];
      #pragma unroll
      for (int i = 0; i < 4; i++) {
        int gm = bm + wm + mt*16 + lgrp*4 + i;
        Out[(size_t)gm * 1024 + gn] = acc[mt][nt][i] + bb;
      }
    }
  }
}

// ---------- flash attention: block = (b,h, 64-row q-tile); 4 waves x 16 q-rows ----------
__global__ __launch_bounds__(256)
void attn_kernel(const unsigned short* __restrict__ Q, const unsigned short* __restrict__ K,
                 const unsigned short* __restrict__ V, unsigned short* __restrict__ O)
{
  const int S = 2048, DK = 64;
  int bh = blockIdx.y;                 // b*16+h
  int qbase = blockIdx.x * 64;
  const int tid = threadIdx.x, lane = tid & 63, w = tid >> 6;
  const int lrow = lane & 15, lgrp = lane >> 4;
  const unsigned short* Qh = Q + (size_t)bh * S * DK;
  const unsigned short* Kh = K + (size_t)bh * S * DK;
  const unsigned short* Vh = V + (size_t)bh * S * DK;

  __shared__ alignas(16) unsigned short Vt[64][64];     // transposed V tile [d][key]
  __shared__ alignas(16) unsigned short Pb[4][16][64];  // per-wave P scratch

  bf16x8 qf[2];
  {
    const unsigned short* qp = Qh + (size_t)(qbase + w*16 + lrow) * DK + lgrp * 8;
    qf[0] = *(const bf16x8*)qp;
    qf[1] = *(const bf16x8*)(qp + 32);
  }
  f32x4 oacc[4];
  #pragma unroll
  for (int i = 0; i < 4; i++) oacc[i] = f32x4{0.f, 0.f, 0.f, 0.f};
  float m_r[4] = {-1e30f, -1e30f, -1e30f, -1e30f};
  float l_r[4] = {0.f, 0.f, 0.f, 0.f};

  for (int kb = 0; kb < S; kb += 64) {
    // stage transposed V tile
    #pragma unroll
    for (int r = 0; r < 2; r++) {
      int key = (tid >> 3) + r * 32;       // 0..63
      int d0  = (tid & 7) * 8;
      u16x8 vv = *(const u16x8*)(Vh + (size_t)(kb + key) * DK + d0);
      #pragma unroll
      for (int j = 0; j < 8; j++) Vt[d0 + j][key] = vv[j];
    }
    __syncthreads();

    // S = Q K^T  (scale already folded into Q)
    f32x4 sacc[4];
    #pragma unroll
    for (int nt = 0; nt < 4; nt++) sacc[nt] = f32x4{0.f, 0.f, 0.f, 0.f};
    #pragma unroll
    for (int ks = 0; ks < 2; ks++) {
      #pragma unroll
      for (int nt = 0; nt < 4; nt++) {
        bf16x8 kf = *(const bf16x8*)(Kh + (size_t)(kb + nt*16 + lrow) * DK + ks*32 + lgrp*8);
        sacc[nt] = __builtin_amdgcn_mfma_f32_16x16x32_bf16(qf[ks], kf, sacc[nt], 0, 0, 0);
      }
    }

    // online softmax (rows r = lgrp*4+i live in 16-lane groups)
    float pm[4];
    #pragma unroll
    for (int i = 0; i < 4; i++)
      pm[i] = fmaxf(fmaxf(sacc[0][i], sacc[1][i]), fmaxf(sacc[2][i], sacc[3][i]));
    #pragma unroll
    for (int off = 1; off < 16; off <<= 1)
      #pragma unroll
      for (int i = 0; i < 4; i++) pm[i] = fmaxf(pm[i], __shfl_xor(pm[i], off, 64));
    float corr[4], rsum[4];
    #pragma unroll
    for (int i = 0; i < 4; i++) {
      float mnew = fmaxf(m_r[i], pm[i]);
      corr[i] = __expf(m_r[i] - mnew);
      m_r[i] = mnew;
      rsum[i] = 0.f;
    }
    #pragma unroll
    for (int nt = 0; nt < 4; nt++) {
      #pragma unroll
      for (int i = 0; i < 4; i++) {
        float p = __expf(sacc[nt][i] - m_r[i]);
        unsigned short pbv = f2bf(p);
        Pb[w][lgrp*4 + i][nt*16 + lrow] = pbv;
        rsum[i] += bf2f(pbv);            // denominator consistent with bf16 numerator
      }
    }
    #pragma unroll
    for (int off = 1; off < 16; off <<= 1)
      #pragma unroll
      for (int i = 0; i < 4; i++) rsum[i] += __shfl_xor(rsum[i], off, 64);
    #pragma unroll
    for (int i = 0; i < 4; i++) l_r[i] = l_r[i] * corr[i] + rsum[i];
    #pragma unroll
    for (int nt = 0; nt < 4; nt++)
      #pragma unroll
      for (int i = 0; i < 4; i++) oacc[nt][i] *= corr[i];

    // O += P V   (A=P from per-wave LDS; B=V from transposed tile)
    #pragma unroll
    for (int ks = 0; ks < 2; ks++) {
      bf16x8 pf = *(const bf16x8*)(&Pb[w][lrow][ks*32 + lgrp*8]);
      #pragma unroll
      for (int nt = 0; nt < 4; nt++) {
        bf16x8 vf = *(const bf16x8*)(&Vt[nt*16 + lrow][ks*32 + lgrp*8]);
        oacc[nt] = __builtin_amdgcn_mfma_f32_16x16x32_bf16(pf, vf, oacc[nt], 0, 0, 0);
      }
    }
    __syncthreads();
  }

  // epilogue: write [B,S,H*64] bf16
  int b = bh >> 4, h = bh & 15;
  #pragma unroll
  for (int nt = 0; nt < 4; nt++) {
    int dd = nt*16 + lrow;
    #pragma unroll
    for (int i = 0; i < 4; i++) {
      int s = qbase + w*16 + lgrp*4 + i;
      float ov = oacc[nt][i] / l_r[i];
      O[((size_t)(b*2048 + s)) * 1024 + h*64 + dd] = f2bf(ov);
    }
  }
}

// ---------- launcher ----------
extern "C" void kernel_launch(void* const* d_in, const int* in_sizes, int n_in,
                              void* d_out, int out_size, void* d_ws, size_t ws_size,
                              hipStream_t stream)
{
  const float* x     = (const float*)d_in[0];
  const float* dwq_w = (const float*)d_in[1];
  const float* dwq_b = (const float*)d_in[2];
  const float* dwk_w = (const float*)d_in[3];
  const float* dwk_b = (const float*)d_in[4];
  const float* dwv_w = (const float*)d_in[5];
  const float* dwv_b = (const float*)d_in[6];
  const float* wq    = (const float*)d_in[7];
  const float* bq    = (const float*)d_in[8];
  const float* wk    = (const float*)d_in[9];
  const float* bk    = (const float*)d_in[10];
  const float* wv    = (const float*)d_in[11];
  const float* bv    = (const float*)d_in[12];
  const float* wo    = (const float*)d_in[13];
  const float* bo    = (const float*)d_in[14];
  float* out = (float*)d_out;

  char* ws = (char*)d_ws;
  const size_t MB = 1024 * 1024;
  unsigned short* cq  = (unsigned short*)(ws + 0);        // 8MB (reused as attn_out)
  unsigned short* ck  = (unsigned short*)(ws + 8*MB);
  unsigned short* cv  = (unsigned short*)(ws + 16*MB);
  unsigned short* qd  = (unsigned short*)(ws + 24*MB);    // [B,H,S,64] bf16
  unsigned short* kd  = (unsigned short*)(ws + 32*MB);
  unsigned short* vd  = (unsigned short*)(ws + 40*MB);
  unsigned short* wqb = (unsigned short*)(ws + 48*MB);
  unsigned short* wkb = (unsigned short*)(ws + 50*MB);
  unsigned short* wvb = (unsigned short*)(ws + 52*MB);
  unsigned short* wob = (unsigned short*)(ws + 54*MB);
  unsigned short* attn_out = cq;                          // cq is dead after gemm_qkv

  cvt_w_kernel<<<dim3(1024, 4), 256, 0, stream>>>(wq, wk, wv, wo, wqb, wkb, wvb, wob);
  conv3_kernel<<<16384, 256, 0, stream>>>(x, dwq_w, dwq_b, dwk_w, dwk_b, dwv_w, dwv_b, cq, ck, cv);
  gemm_qkv_kernel<<<dim3(8, 32, 3), 256, 0, stream>>>(cq, ck, cv, wqb, wkb, wvb, bq, bk, bv, qd, kd, vd);
  attn_kernel<<<dim3(32, 32), 256, 0, stream>>>(qd, kd, vd, attn_out);
  gemm_out_kernel<<<dim3(8, 32), 256, 0, stream>>>(attn_out, wob, bo, out);
}